// Round 8
// baseline (398.428 us; speedup 1.0000x reference)
//
#include <hip/hip_runtime.h>
#include <math.h>

#define B_   16
#define N_   2048
#define KNN  20
#define OD   64
#define M_TOT (B_ * N_ * KNN)
#define PPB  64
#define CAP  96          // per-sub-bucket capacity; used buckets proven <= 89

typedef unsigned long long u64;
typedef unsigned int u32;
typedef unsigned short u16;

// ---------------------------------------------------------------------------
// K0: pack x (B,3,N strided) -> float4 (x,y,z,||x||^2) in ws.
// ---------------------------------------------------------------------------
__global__ __launch_bounds__(256) void k0_pack(const float* __restrict__ x,
                                               float4* __restrict__ g) {
    int i = blockIdx.x * 256 + threadIdx.x;     // 32768 total
    int b = i >> 11, n = i & (N_ - 1);
    const float* xb = x + b * 3 * N_;
    float x0 = xb[n], x1 = xb[N_ + n], x2 = xb[2 * N_ + n];
    float xx = x0 * x0;
    xx = fmaf(x1, x1, xx);
    xx = fmaf(x2, x2, xx);
    g[i] = make_float4(x0, x1, x2, xx);
}

// ---------------------------------------------------------------------------
// K1: two-dense-pass KNN select. 512 blocks x 1024 thr (16 waves), 64 pts/blk,
// lane = point, wave w scans j in [w*128, w*128+128).
// Pass A: 14 octave float-edge LT-counts in registers (no LDS in loop).
// merge1: smallest octave edge T with count >= 20 (exists: span argument).
// Pass B: collect nk < T into 4 quarter-octave sub-buckets, lane-major LDS
//   (coll[q][pos][lane] -> 2-way bank alias only; fixes rounds 3-7's 64-way
//   same-bank push serialization). Quarter grid == (nk>>21) grid of proven
//   rounds -> used-bucket cumulative <= 89 < CAP.
// Pass C: q* = smallest sub-bucket with cum >= 20; exact top-20 u64 chain
//   over buckets 0..q* (lax.top_k semantics: value desc, tie -> lower j;
//   bit-identical pd chain). Emits 27 BN moments + e-vectors for k3.
// ---------------------------------------------------------------------------
__global__ __launch_bounds__(1024, 8) void k1_knn(const float4* __restrict__ g,
                                                  float* __restrict__ stats,
                                                  float4* __restrict__ evec) {
    __shared__ u32 cntb[7][16][PPB];        // 28 KB packed u16 count pairs
    __shared__ u16 coll[4 * CAP * PPB];     // 48 KB  [q][pos][lane]
    __shared__ u32 pcnt[4][PPB];            // 1 KB   [q][lane]
    __shared__ u32 topv[PPB];

    const int b     = blockIdx.x >> 5;      // 32 chunks of 64 points per batch
    const int chunk = blockIdx.x & 31;
    const int t     = threadIdx.x;
    const float4* gb = g + (b << 11);

    const int lane = t & 63;
    const int il0  = chunk << 6;
    const int il   = il0 + lane;
    const float4 pi = gb[il];

    if (t < 256) pcnt[t >> 6][t & 63] = 0;

    const int jw = __builtin_amdgcn_readfirstlane((t >> 6) << 7);
    int jv;                                  // opaque -> forces VMEM loads
    asm volatile("v_mov_b32 %0, %1" : "=v"(jv) : "s"(jw));

    // ---- pass A: 14 octave LT-counts (registers only) ---------------------
    const float negedge[14] = {
        -0.00390625f, -0.0078125f, -0.015625f, -0.03125f, -0.0625f, -0.125f,
        -0.25f, -0.5f, -1.f, -2.f, -4.f, -8.f, -16.f, -32.f};
    u32 cnt[14] = {0,0,0,0,0,0,0,0,0,0,0,0,0,0};
    for (int jj = 0; jj < 128; jj += 4) {
        float4 c4[4];
#pragma unroll
        for (int u = 0; u < 4; ++u) c4[u] = gb[jv + jj + u];
#pragma unroll
        for (int u = 0; u < 4; ++u) {
            float dot = pi.x * c4[u].x;
            dot = fmaf(pi.y, c4[u].y, dot);
            dot = fmaf(pi.z, c4[u].z, dot);
            float pd = fmaf(2.f, dot, -pi.w) - c4[u].w;  // exactly 0 for i==j
#pragma unroll
            for (int k = 0; k < 14; ++k) cnt[k] += (pd > negedge[k]) ? 1u : 0u;
        }
    }
    {
        const int w = t >> 6;
#pragma unroll
        for (int p = 0; p < 7; ++p)
            cntb[p][w][lane] = cnt[2 * p] | (cnt[2 * p + 1] << 16);
    }
    __syncthreads();

    // ---- merge1: pick octave edge T ---------------------------------------
    if (t < PPB) {
        u32 tot[14] = {0,0,0,0,0,0,0,0,0,0,0,0,0,0};
        for (int ww = 0; ww < 16; ++ww) {
#pragma unroll
            for (int p = 0; p < 7; ++p) {
                u32 v = cntb[p][ww][t];
                tot[2 * p]     += v & 0xFFFFu;
                tot[2 * p + 1] += v >> 16;
            }
        }
        int ks = 13;
#pragma unroll
        for (int k = 12; k >= 0; --k) if (tot[k] >= KNN) ks = k;
        topv[t] = (u32)(119 + ks) << 23;     // float bits of 2^(-8+ks)
    }
    __syncthreads();

    // ---- pass B: collect below T into 4 quarter sub-buckets ---------------
    {
        const u32 T  = topv[lane];
        const u32 s1 = T - 0x600000u;        // bottom + 1 quarter
        const u32 s2 = T - 0x400000u;
        const u32 s3 = T - 0x200000u;
        for (int jj = 0; jj < 128; jj += 4) {
            float4 c4[4];
#pragma unroll
            for (int u = 0; u < 4; ++u) c4[u] = gb[jv + jj + u];
#pragma unroll
            for (int u = 0; u < 4; ++u) {
                float dot = pi.x * c4[u].x;
                dot = fmaf(pi.y, c4[u].y, dot);
                dot = fmaf(pi.z, c4[u].z, dot);
                float pd = fmaf(2.f, dot, -pi.w) - c4[u].w;
                u32 nk = __float_as_uint(pd) & 0x7FFFFFFFu;
                u32 qq = ((nk >= s1) ? 1u : 0u) + ((nk >= s2) ? 1u : 0u) +
                         ((nk >= s3) ? 1u : 0u);
                if (nk < T) {
                    u32 pos = atomicAdd(&pcnt[qq][lane], 1u);  // bank=lane&31
                    if (pos < CAP)
                        coll[((qq * CAP + pos) << 6) + lane] = (u16)(jw + jj + u);
                }
            }
        }
    }
    __syncthreads();

    // ---- pass C: q*, exact top-20, evec write, moments --------------------
    if (t < PPB) {
        u32 c0 = pcnt[0][t], c1 = pcnt[1][t], c2 = pcnt[2][t], c3 = pcnt[3][t];
        (void)c3;
        int qs; u32 cum = c0;
        if (cum >= KNN) qs = 0;
        else { cum += c1; if (cum >= KNN) qs = 1;
               else { cum += c2; qs = (cum >= KNN) ? 2 : 3; } }

        u64 d[KNN];
#pragma unroll
        for (int q = 0; q < KNN; ++q) d[q] = 0ull;
        for (int qq = 0; qq <= qs; ++qq) {
            const int cc = min((int)pcnt[qq][t], CAP);
            for (int e = 0; e < cc; ++e) {
                int j = coll[((qq * CAP + e) << 6) + t];
                float4 pj = gb[j];
                float dot = pi.x * pj.x;
                dot = fmaf(pi.y, pj.y, dot);
                dot = fmaf(pi.z, pj.z, dot);
                float pd = fmaf(2.f, dot, -pi.w) - pj.w;   // bit-identical
                u32 uu = __float_as_uint(pd);
                u32 mono = ((int)uu < 0) ? ~uu : (uu | 0x80000000u);
                u64 v = ((u64)mono << 32) | (u32)(~j);
                if (v > d[KNN - 1]) {
#pragma unroll
                    for (int q = 0; q < KNN; ++q) {        // sorted CE chain
                        u64 hi = (v > d[q]) ? v : d[q];
                        u64 lo = (v > d[q]) ? d[q] : v;
                        d[q] = hi; v = lo;
                    }
                }
            }
        }

        float4* ep = evec + ((b * KNN) << 11) + il;        // stride 2048 per r
        float se0 = 0.f, se1 = 0.f, se2 = 0.f;
        float see[6] = {0.f, 0.f, 0.f, 0.f, 0.f, 0.f};
#pragma unroll
        for (int r = 0; r < KNN; ++r) {
            int j = (int)(~(u32)d[r]);
            float4 pj = gb[j];
            float e0 = pj.x - pi.x, e1 = pj.y - pi.y, e2 = pj.z - pi.z;
            ep[r << 11] = make_float4(e0, e1, e2, 0.f);    // coalesced per r
            se0 += e0; se1 += e1; se2 += e2;
            see[0] = fmaf(e0, e0, see[0]);
            see[1] = fmaf(e0, e1, see[1]);
            see[2] = fmaf(e0, e2, see[2]);
            see[3] = fmaf(e1, e1, see[3]);
            see[4] = fmaf(e1, e2, see[4]);
            see[5] = fmaf(e2, e2, see[5]);
        }
        float cx = pi.x, cy = pi.y, cz = pi.z;
        float v[27];
        v[0] = se0; v[1] = se1; v[2] = se2;
        v[3] = 20.f * cx; v[4] = 20.f * cy; v[5] = 20.f * cz;
        v[6]  = see[0];
        v[7]  = see[1];
        v[8]  = see[2];
        v[9]  = se0 * cx;
        v[10] = se0 * cy;
        v[11] = se0 * cz;
        v[12] = see[3];
        v[13] = see[4];
        v[14] = se1 * cx;
        v[15] = se1 * cy;
        v[16] = se1 * cz;
        v[17] = see[5];
        v[18] = se2 * cx;
        v[19] = se2 * cy;
        v[20] = se2 * cz;
        v[21] = 20.f * cx * cx;
        v[22] = 20.f * cx * cy;
        v[23] = 20.f * cx * cz;
        v[24] = 20.f * cy * cy;
        v[25] = 20.f * cy * cz;
        v[26] = 20.f * cz * cz;

#pragma unroll
        for (int m = 0; m < 27; ++m) {
            float sm = v[m];
#pragma unroll
            for (int off = 32; off > 0; off >>= 1) sm += __shfl_xor(sm, off);
            if (t == 0) atomicAdd(stats + m, sm);
        }
    }
}

// ---------------------------------------------------------------------------
// K2: finalize BN stats -> fused weights W' = scale*W, shift = beta - mean*scale
// ---------------------------------------------------------------------------
__global__ void k2_fin(const float* __restrict__ stats, const float* __restrict__ W,
                       const float* __restrict__ bnw, const float* __restrict__ bnb,
                       float* __restrict__ wp) {
    const int o = threadIdx.x;  // 64 threads
    float m[6];
#pragma unroll
    for (int c = 0; c < 6; ++c) m[c] = stats[c];
    float S[6][6];
    int p = 6;
#pragma unroll
    for (int a = 0; a < 6; ++a)
#pragma unroll
        for (int bb = a; bb < 6; ++bb) { S[a][bb] = stats[p]; S[bb][a] = stats[p]; ++p; }
    float w[6];
#pragma unroll
    for (int c = 0; c < 6; ++c) w[c] = W[o * 6 + c];

    const float invM = 1.f / (float)M_TOT;
    float mean = 0.f;
#pragma unroll
    for (int c = 0; c < 6; ++c) mean += w[c] * m[c];
    mean *= invM;
    float ey2 = 0.f;
#pragma unroll
    for (int a = 0; a < 6; ++a)
#pragma unroll
        for (int bb = 0; bb < 6; ++bb) ey2 += w[a] * w[bb] * S[a][bb];
    ey2 *= invM;
    float var   = ey2 - mean * mean;
    float scale = bnw[o] * rsqrtf(var + 1e-5f);
    float shift = bnb[o] - mean * scale;
#pragma unroll
    for (int c = 0; c < 6; ++c) wp[o * 8 + c] = w[c] * scale;
    wp[o * 8 + 6] = shift;
    wp[o * 8 + 7] = 0.f;
}

// ---------------------------------------------------------------------------
// K3: zero-gather output. e-vectors pre-computed by k1 (evec[b][r][n]),
// streamed coalesced into LDS. 512 blocks x 256 thr: 64 points/block,
// 4 threads/point x 16 channels (2 register blocks of 8). Stores coalesced.
// ---------------------------------------------------------------------------
__global__ __launch_bounds__(256) void k3_out(const float4* __restrict__ g,
                                              const float* __restrict__ wp,
                                              const float4* __restrict__ evec,
                                              float* __restrict__ out) {
    __shared__ float4 sev[PPB * KNN];   // 20 KB  [r][n]
    __shared__ float  lwp[OD * 8];      // 2 KB

    const int b     = blockIdx.x >> 5;  // 32 chunks of 64 points per batch
    const int chunk = blockIdx.x & 31;
    const int t     = threadIdx.x;
    const int n0    = chunk << 6;

    for (int q = t; q < OD * 8; q += 256) lwp[q] = wp[q];
    for (int i = t; i < PPB * KNN; i += 256) {
        int r = i >> 6, nn = i & 63;
        sev[i] = evec[((b * KNN + r) << 11) + n0 + nn];   // coalesced rows
    }
    __syncthreads();

    const int nl  = t & 63;             // lane = point -> coalesced stores
    const int sub = t >> 6;             // channel quarter (wave-uniform)
    const int n   = n0 + nl;
    const float4 pi = g[(b << 11) + n];
    float* ob = out + (size_t)b * OD * N_ + n;

#pragma unroll
    for (int cb = 0; cb < 2; ++cb) {
        const int o0 = sub * 16 + cb * 8;
        float w0[8], w1[8], w2[8], bs[8], acc[8];
#pragma unroll
        for (int c = 0; c < 8; ++c) {
            const float* wo = &lwp[(o0 + c) * 8];
            w0[c] = wo[0]; w1[c] = wo[1]; w2[c] = wo[2];
            float base = wo[6];
            base = fmaf(wo[3], pi.x, base);
            base = fmaf(wo[4], pi.y, base);
            base = fmaf(wo[5], pi.z, base);
            bs[c] = base;
            acc[c] = 0.f;               // relu folded into init
        }
#pragma unroll
        for (int r = 0; r < KNN; ++r) {
            float4 e = sev[(r << 6) + nl];
#pragma unroll
            for (int c = 0; c < 8; ++c) {
                float y = bs[c];
                y = fmaf(w0[c], e.x, y);
                y = fmaf(w1[c], e.y, y);
                y = fmaf(w2[c], e.z, y);
                acc[c] = fmaxf(acc[c], y);
            }
        }
#pragma unroll
        for (int c = 0; c < 8; ++c) ob[(size_t)(o0 + c) << 11] = acc[c];
    }
}

// ---------------------------------------------------------------------------
extern "C" void kernel_launch(void* const* d_in, const int* in_sizes, int n_in,
                              void* d_out, int out_size, void* d_ws, size_t ws_size,
                              hipStream_t stream) {
    const float* x   = (const float*)d_in[0];
    const float* W   = (const float*)d_in[1];
    const float* bnw = (const float*)d_in[2];
    const float* bnb = (const float*)d_in[3];
    float* out = (float*)d_out;

    float*  stats = (float*)d_ws;                          // 27 floats
    float*  wp    = (float*)((char*)d_ws + 1024);          // 64*8 floats
    float4* pts_g = (float4*)((char*)d_ws + 4096);         // 512 KB
    float4* evec  = (float4*)((char*)d_ws + 4096 + 524288);// 10 MB [b][r][n]

    hipMemsetAsync(d_ws, 0, 128, stream);
    k0_pack<<<dim3(128), dim3(256), 0, stream>>>(x, pts_g);
    k1_knn<<<dim3(512), dim3(1024), 0, stream>>>(pts_g, stats, evec);
    k2_fin<<<dim3(1), dim3(64), 0, stream>>>(stats, W, bnw, bnb, wp);
    k3_out<<<dim3(512), dim3(256), 0, stream>>>(pts_g, wp, evec, out);
}

// Round 11
// 290.460 us; speedup vs baseline: 1.3717x; 1.3717x over previous
//
#include <hip/hip_runtime.h>
#include <math.h>

#define B_   16
#define N_   2048
#define KNN  20
#define OD   64
#define M_TOT (B_ * N_ * KNN)
#define PPB  64
#define CAP  96          // per-sub-bucket capacity; used buckets proven <= 89

typedef unsigned long long u64;
typedef unsigned int u32;
typedef unsigned short u16;

// ---------------------------------------------------------------------------
// K0: pack x (B,3,N strided) -> float4 (x,y,z,||x||^2) in ws.
// ---------------------------------------------------------------------------
__global__ __launch_bounds__(256) void k0_pack(const float* __restrict__ x,
                                               float4* __restrict__ g) {
    int i = blockIdx.x * 256 + threadIdx.x;     // 32768 total
    int b = i >> 11, n = i & (N_ - 1);
    const float* xb = x + b * 3 * N_;
    float x0 = xb[n], x1 = xb[N_ + n], x2 = xb[2 * N_ + n];
    float xx = x0 * x0;
    xx = fmaf(x1, x1, xx);
    xx = fmaf(x2, x2, xx);
    g[i] = make_float4(x0, x1, x2, xx);
}

// ---------------------------------------------------------------------------
// K1: two-dense-pass KNN select (round-8 structure, round-7 register regime).
// 512 blocks x 512 thr (8 waves), 64 pts/block, lane = point, wave w scans
// j in [w*256, w*256+256). VMEM uniform loads with imm offsets.
// Pass A: 14 octave float-edge LT-counts in registers (2 VALU/edge).
// merge1: smallest octave edge T with count >= 20.
// Pass B: collect nk < T into 4 quarter-octave sub-buckets, lane-major LDS
//   (2-way bank alias only). Quarter grid == proven rounds-3..8 grid ->
//   used-bucket counts <= 89 < CAP.
// Pass C: exact top-20 u64 chain over buckets 0..q* (lax.top_k semantics:
//   value desc, tie -> lower j; bit-identical pd). Emits 27 BN moments +
//   e-vectors for k3.
// ---------------------------------------------------------------------------
__global__ __launch_bounds__(512, 4) void k1_knn(const float4* __restrict__ g,
                                                 float* __restrict__ stats,
                                                 float4* __restrict__ evec) {
    __shared__ u32 cntb[7][8][PPB];         // 14 KB packed u16 count pairs
    __shared__ u16 coll[4 * CAP * PPB];     // 48 KB  [q][pos][lane]
    __shared__ u32 pcnt[4][PPB];            // 1 KB   [q][lane]
    __shared__ u32 topv[PPB];

    const int b     = blockIdx.x >> 5;      // 32 chunks of 64 points per batch
    const int chunk = blockIdx.x & 31;
    const int t     = threadIdx.x;
    const float4* gb = g + (b << 11);

    const int lane = t & 63;
    const int il0  = chunk << 6;
    const int il   = il0 + lane;
    const float4 pi = gb[il];

    if (t < 256) pcnt[t >> 6][t & 63] = 0;

    const int jw = __builtin_amdgcn_readfirstlane((t >> 6) << 8);
    int jv;                                  // opaque -> forces VMEM loads
    asm volatile("v_mov_b32 %0, %1" : "=v"(jv) : "s"(jw));

    // ---- pass A: 14 octave LT-counts (registers only) ---------------------
    const float negedge[14] = {
        -0.00390625f, -0.0078125f, -0.015625f, -0.03125f, -0.0625f, -0.125f,
        -0.25f, -0.5f, -1.f, -2.f, -4.f, -8.f, -16.f, -32.f};
    u32 cnt[14] = {0,0,0,0,0,0,0,0,0,0,0,0,0,0};
    for (int jj = 0; jj < 256; jj += 4) {
        float4 c4[4];
#pragma unroll
        for (int u = 0; u < 4; ++u) c4[u] = gb[jv + jj + u];
#pragma unroll
        for (int u = 0; u < 4; ++u) {
            float dot = pi.x * c4[u].x;
            dot = fmaf(pi.y, c4[u].y, dot);
            dot = fmaf(pi.z, c4[u].z, dot);
            float pd = fmaf(2.f, dot, -pi.w) - c4[u].w;  // exactly 0 for i==j
#pragma unroll
            for (int k = 0; k < 14; ++k) cnt[k] += (pd > negedge[k]) ? 1u : 0u;
        }
    }
    {
        const int w = t >> 6;
#pragma unroll
        for (int p = 0; p < 7; ++p)
            cntb[p][w][lane] = cnt[2 * p] | (cnt[2 * p + 1] << 16);
    }
    __syncthreads();

    // ---- merge1: pick octave edge T ---------------------------------------
    if (t < PPB) {
        u32 tot[14] = {0,0,0,0,0,0,0,0,0,0,0,0,0,0};
        for (int ww = 0; ww < 8; ++ww) {
#pragma unroll
            for (int p = 0; p < 7; ++p) {
                u32 v = cntb[p][ww][t];
                tot[2 * p]     += v & 0xFFFFu;
                tot[2 * p + 1] += v >> 16;
            }
        }
        int ks = 13;
#pragma unroll
        for (int k = 12; k >= 0; --k) if (tot[k] >= KNN) ks = k;
        topv[t] = (u32)(119 + ks) << 23;     // float bits of 2^(-8+ks)
    }
    __syncthreads();

    // ---- pass B: collect below T into 4 quarter sub-buckets ---------------
    {
        const u32 T  = topv[lane];
        const u32 s1 = T - 0x600000u;        // octave bottom + 1 quarter
        const u32 s2 = T - 0x400000u;
        const u32 s3 = T - 0x200000u;
        for (int jj = 0; jj < 256; jj += 4) {
            float4 c4[4];
#pragma unroll
            for (int u = 0; u < 4; ++u) c4[u] = gb[jv + jj + u];
#pragma unroll
            for (int u = 0; u < 4; ++u) {
                float dot = pi.x * c4[u].x;
                dot = fmaf(pi.y, c4[u].y, dot);
                dot = fmaf(pi.z, c4[u].z, dot);
                float pd = fmaf(2.f, dot, -pi.w) - c4[u].w;
                u32 nk = __float_as_uint(pd) & 0x7FFFFFFFu;
                u32 qq = ((nk >= s1) ? 1u : 0u) + ((nk >= s2) ? 1u : 0u) +
                         ((nk >= s3) ? 1u : 0u);
                if (nk < T) {
                    u32 pos = atomicAdd(&pcnt[qq][lane], 1u);  // bank=lane&31
                    if (pos < CAP)
                        coll[((qq * CAP + pos) << 6) + lane] = (u16)(jw + jj + u);
                }
            }
        }
    }
    __syncthreads();

    // ---- pass C: q*, exact top-20, evec write, moments --------------------
    if (t < PPB) {
        u32 c0 = pcnt[0][t], c1 = pcnt[1][t], c2 = pcnt[2][t];
        int qs; u32 cum = c0;
        if (cum >= KNN) qs = 0;
        else { cum += c1; if (cum >= KNN) qs = 1;
               else { cum += c2; qs = (cum >= KNN) ? 2 : 3; } }

        u64 d[KNN];
#pragma unroll
        for (int q = 0; q < KNN; ++q) d[q] = 0ull;
        for (int qq = 0; qq <= qs; ++qq) {
            const int cc = min((int)pcnt[qq][t], CAP);
            for (int e = 0; e < cc; ++e) {
                int j = coll[((qq * CAP + e) << 6) + t];
                float4 pj = gb[j];
                float dot = pi.x * pj.x;
                dot = fmaf(pi.y, pj.y, dot);
                dot = fmaf(pi.z, pj.z, dot);
                float pd = fmaf(2.f, dot, -pi.w) - pj.w;   // bit-identical
                u32 uu = __float_as_uint(pd);
                u32 mono = ((int)uu < 0) ? ~uu : (uu | 0x80000000u);
                u64 v = ((u64)mono << 32) | (u32)(~j);
                if (v > d[KNN - 1]) {
#pragma unroll
                    for (int q = 0; q < KNN; ++q) {        // sorted CE chain
                        u64 hi = (v > d[q]) ? v : d[q];
                        u64 lo = (v > d[q]) ? d[q] : v;
                        d[q] = hi; v = lo;
                    }
                }
            }
        }

        float4* ep = evec + ((b * KNN) << 11) + il;        // stride 2048 per r
        float se0 = 0.f, se1 = 0.f, se2 = 0.f;
        float see[6] = {0.f, 0.f, 0.f, 0.f, 0.f, 0.f};
#pragma unroll
        for (int r = 0; r < KNN; ++r) {
            int j = (int)(~(u32)d[r]);
            float4 pj = gb[j];
            float e0 = pj.x - pi.x, e1 = pj.y - pi.y, e2 = pj.z - pi.z;
            ep[r << 11] = make_float4(e0, e1, e2, 0.f);    // coalesced per r
            se0 += e0; se1 += e1; se2 += e2;
            see[0] = fmaf(e0, e0, see[0]);
            see[1] = fmaf(e0, e1, see[1]);
            see[2] = fmaf(e0, e2, see[2]);
            see[3] = fmaf(e1, e1, see[3]);
            see[4] = fmaf(e1, e2, see[4]);
            see[5] = fmaf(e2, e2, see[5]);
        }
        float cx = pi.x, cy = pi.y, cz = pi.z;
        float v[27];
        v[0] = se0; v[1] = se1; v[2] = se2;
        v[3] = 20.f * cx; v[4] = 20.f * cy; v[5] = 20.f * cz;
        v[6]  = see[0];
        v[7]  = see[1];
        v[8]  = see[2];
        v[9]  = se0 * cx;
        v[10] = se0 * cy;
        v[11] = se0 * cz;
        v[12] = see[3];
        v[13] = see[4];
        v[14] = se1 * cx;
        v[15] = se1 * cy;
        v[16] = se1 * cz;
        v[17] = see[5];
        v[18] = se2 * cx;
        v[19] = se2 * cy;
        v[20] = se2 * cz;
        v[21] = 20.f * cx * cx;
        v[22] = 20.f * cx * cy;
        v[23] = 20.f * cx * cz;
        v[24] = 20.f * cy * cy;
        v[25] = 20.f * cy * cz;
        v[26] = 20.f * cz * cz;

#pragma unroll
        for (int m = 0; m < 27; ++m) {
            float sm = v[m];
#pragma unroll
            for (int off = 32; off > 0; off >>= 1) sm += __shfl_xor(sm, off);
            if (t == 0) atomicAdd(stats + m, sm);
        }
    }
}

// ---------------------------------------------------------------------------
// K2: finalize BN stats -> fused weights W' = scale*W, shift = beta - mean*scale
// ---------------------------------------------------------------------------
__global__ void k2_fin(const float* __restrict__ stats, const float* __restrict__ W,
                       const float* __restrict__ bnw, const float* __restrict__ bnb,
                       float* __restrict__ wp) {
    const int o = threadIdx.x;  // 64 threads
    float m[6];
#pragma unroll
    for (int c = 0; c < 6; ++c) m[c] = stats[c];
    float S[6][6];
    int p = 6;
#pragma unroll
    for (int a = 0; a < 6; ++a)
#pragma unroll
        for (int bb = a; bb < 6; ++bb) { S[a][bb] = stats[p]; S[bb][a] = stats[p]; ++p; }
    float w[6];
#pragma unroll
    for (int c = 0; c < 6; ++c) w[c] = W[o * 6 + c];

    const float invM = 1.f / (float)M_TOT;
    float mean = 0.f;
#pragma unroll
    for (int c = 0; c < 6; ++c) mean += w[c] * m[c];
    mean *= invM;
    float ey2 = 0.f;
#pragma unroll
    for (int a = 0; a < 6; ++a)
#pragma unroll
        for (int bb = 0; bb < 6; ++bb) ey2 += w[a] * w[bb] * S[a][bb];
    ey2 *= invM;
    float var   = ey2 - mean * mean;
    float scale = bnw[o] * rsqrtf(var + 1e-5f);
    float shift = bnb[o] - mean * scale;
#pragma unroll
    for (int c = 0; c < 6; ++c) wp[o * 8 + c] = w[c] * scale;
    wp[o * 8 + 6] = shift;
    wp[o * 8 + 7] = 0.f;
}

// ---------------------------------------------------------------------------
// K3: zero-gather output. e-vectors pre-computed by k1 (evec[b][r][n]),
// streamed coalesced into LDS. 512 blocks x 256 thr: 64 points/block,
// 4 threads/point x 16 channels (2 register blocks of 8). Stores coalesced.
// ---------------------------------------------------------------------------
__global__ __launch_bounds__(256) void k3_out(const float4* __restrict__ g,
                                              const float* __restrict__ wp,
                                              const float4* __restrict__ evec,
                                              float* __restrict__ out) {
    __shared__ float4 sev[PPB * KNN];   // 20 KB  [r][n]
    __shared__ float  lwp[OD * 8];      // 2 KB

    const int b     = blockIdx.x >> 5;  // 32 chunks of 64 points per batch
    const int chunk = blockIdx.x & 31;
    const int t     = threadIdx.x;
    const int n0    = chunk << 6;

    for (int q = t; q < OD * 8; q += 256) lwp[q] = wp[q];
    for (int i = t; i < PPB * KNN; i += 256) {
        int r = i >> 6, nn = i & 63;
        sev[i] = evec[((b * KNN + r) << 11) + n0 + nn];   // coalesced rows
    }
    __syncthreads();

    const int nl  = t & 63;             // lane = point -> coalesced stores
    const int sub = t >> 6;             // channel quarter (wave-uniform)
    const int n   = n0 + nl;
    const float4 pi = g[(b << 11) + n];
    float* ob = out + (size_t)b * OD * N_ + n;

#pragma unroll
    for (int cb = 0; cb < 2; ++cb) {
        const int o0 = sub * 16 + cb * 8;
        float w0[8], w1[8], w2[8], bs[8], acc[8];
#pragma unroll
        for (int c = 0; c < 8; ++c) {
            const float* wo = &lwp[(o0 + c) * 8];
            w0[c] = wo[0]; w1[c] = wo[1]; w2[c] = wo[2];
            float base = wo[6];
            base = fmaf(wo[3], pi.x, base);
            base = fmaf(wo[4], pi.y, base);
            base = fmaf(wo[5], pi.z, base);
            bs[c] = base;
            acc[c] = 0.f;               // relu folded into init
        }
#pragma unroll
        for (int r = 0; r < KNN; ++r) {
            float4 e = sev[(r << 6) + nl];
#pragma unroll
            for (int c = 0; c < 8; ++c) {
                float y = bs[c];
                y = fmaf(w0[c], e.x, y);
                y = fmaf(w1[c], e.y, y);
                y = fmaf(w2[c], e.z, y);
                acc[c] = fmaxf(acc[c], y);
            }
        }
#pragma unroll
        for (int c = 0; c < 8; ++c) ob[(size_t)(o0 + c) << 11] = acc[c];
    }
}

// ---------------------------------------------------------------------------
extern "C" void kernel_launch(void* const* d_in, const int* in_sizes, int n_in,
                              void* d_out, int out_size, void* d_ws, size_t ws_size,
                              hipStream_t stream) {
    const float* x   = (const float*)d_in[0];
    const float* W   = (const float*)d_in[1];
    const float* bnw = (const float*)d_in[2];
    const float* bnb = (const float*)d_in[3];
    float* out = (float*)d_out;

    float*  stats = (float*)d_ws;                          // 27 floats
    float*  wp    = (float*)((char*)d_ws + 1024);          // 64*8 floats
    float4* pts_g = (float4*)((char*)d_ws + 4096);         // 512 KB
    float4* evec  = (float4*)((char*)d_ws + 4096 + 524288);// 10 MB [b][r][n]

    hipMemsetAsync(d_ws, 0, 128, stream);
    k0_pack<<<dim3(128), dim3(256), 0, stream>>>(x, pts_g);
    k1_knn<<<dim3(512), dim3(512), 0, stream>>>(pts_g, stats, evec);
    k2_fin<<<dim3(1), dim3(64), 0, stream>>>(stats, W, bnw, bnb, wp);
    k3_out<<<dim3(512), dim3(256), 0, stream>>>(pts_g, wp, evec, out);
}